// Round 18
// baseline (419.806 us; speedup 1.0000x reference)
//
#include <hip/hip_runtime.h>
#include <hip/hip_bf16.h>
#include <math.h>

typedef __bf16 bf16x8 __attribute__((ext_vector_type(8)));
typedef __bf16 bf16x4 __attribute__((ext_vector_type(4)));
typedef float  f32x4  __attribute__((ext_vector_type(4)));

#define DEV static __device__ __forceinline__

DEV unsigned short f2bf(float f) {
    unsigned u = __builtin_bit_cast(unsigned, f);
    u += 0x7fffu + ((u >> 16) & 1u);     // RNE
    return (unsigned short)(u >> 16);
}
DEV float bf2f(unsigned short u) {
    unsigned x = ((unsigned)u) << 16;
    return __builtin_bit_cast(float, x);
}

// ---------------- fused fp32 -> bf16 weight convert (all 4 weights) ----------------
__global__ void k_cvtall(const float* __restrict__ a, const float* __restrict__ b,
                         const float* __restrict__ c, const float* __restrict__ d,
                         unsigned short* __restrict__ oa, unsigned short* __restrict__ ob,
                         unsigned short* __restrict__ oc, unsigned short* __restrict__ od) {
    size_t i = (size_t)blockIdx.x * 1024 + threadIdx.x * 4;
    const float* src; unsigned short* dst; size_t off;
    if (i < 3145728)      { src = a; dst = oa; off = i; }
    else if (i < 4194304) { src = b; dst = ob; off = i - 3145728; }
    else if (i < 8388608) { src = c; dst = oc; off = i - 4194304; }
    else                  { src = d; dst = od; off = i - 8388608; }
    float4 v = *(const float4*)(src + off);
    ushort4 o;
    o.x = f2bf(v.x); o.y = f2bf(v.y); o.z = f2bf(v.z); o.w = f2bf(v.w);
    *(ushort4*)(dst + off) = o;
}

// ---------------- adaLN: ada = silu(c) @ Wada^T + bada ----------------
__global__ void k_ada(const float* __restrict__ c, const float* __restrict__ Wada,
                      const float* __restrict__ bada, float* __restrict__ ada) {
    __shared__ float sc[1024];
    int b = blockIdx.x;
    int tid = threadIdx.x;
    for (int k = tid; k < 1024; k += 256) {
        float x = c[b * 1024 + k];
        sc[k] = x / (1.f + __expf(-x));
    }
    __syncthreads();
    int wid = tid >> 6, lane = tid & 63;
    int n = blockIdx.y * 4 + wid;
    const float* wr = Wada + (size_t)n * 1024;
    float acc = 0.f;
    #pragma unroll
    for (int k = 0; k < 1024; k += 64) acc += sc[k + lane] * wr[k + lane];
    #pragma unroll
    for (int o = 32; o; o >>= 1) acc += __shfl_xor(acc, o);
    if (lane == 0) ada[b * 6144 + n] = acc + bada[n];
}

// ---------------- fused rmsnorm + modulate -> bf16 (msa branch) ----------------
__global__ void k_norm_mod(const float* __restrict__ x, const float* __restrict__ ada,
                           const float* __restrict__ g, unsigned short* __restrict__ h,
                           int shift_off, int scale_off) {
    int row = blockIdx.x;
    int b = row >> 10;
    int tid = threadIdx.x;
    float4 v = *(const float4*)(x + (size_t)row * 1024 + tid * 4);
    float ss = v.x * v.x + v.y * v.y + v.z * v.z + v.w * v.w;
    #pragma unroll
    for (int o = 32; o; o >>= 1) ss += __shfl_xor(ss, o);
    __shared__ float red[4];
    int wid = tid >> 6, lane = tid & 63;
    if (lane == 0) red[wid] = ss;
    __syncthreads();
    float nrm = sqrtf(red[0] + red[1] + red[2] + red[3]);
    float f = g[0] * 32.f / fmaxf(nrm, 1e-12f);
    float4 s4 = *(const float4*)(ada + b * 6144 + scale_off + tid * 4);
    float4 h4 = *(const float4*)(ada + b * 6144 + shift_off + tid * 4);
    ushort4 o;
    o.x = f2bf(v.x * f * (1.f + s4.x) + h4.x);
    o.y = f2bf(v.y * f * (1.f + s4.y) + h4.y);
    o.z = f2bf(v.z * f * (1.f + s4.z) + h4.z);
    o.w = f2bf(v.w * f * (1.f + s4.w) + h4.w);
    *(ushort4*)(h + (size_t)row * 1024 + tid * 4) = o;
}

// ============ m97-structure bf16 GEMM, BK=64, optional split-K ============
// 128x128 tile, BK=64, 256 threads (4 waves), 32KB LDS single-buffered.
// __launch_bounds__(256,4): 60 VGPR, NO spills (R8 proved (256,5) spills acc -> 2.3x slower).
// Rows = 128B = 8 granules; LDS slot = granule ^ (row&7) (measured ZERO bank conflicts),
// applied involutively on the global source. DO NOT replace with deep pipelines:
// R5 (3-buf ring) and R11 (8-phase port) both measured SLOWER (113/102 vs 84 us).
// EPI: 0 = +bias -> bf16 | 2 = gelu(+bias) -> bf16 | 4 = raw partial -> bf16 at sp*M*N
//      5 = qkv: Q/K fused per-head rms-norm -> outH; V transposed through LDS -> Vtg
template <int EPI>
__global__ __launch_bounds__(256, 4)
void k_gemm5(const unsigned short* __restrict__ A, const unsigned short* __restrict__ Bw,
             const float* __restrict__ bias, int N, int K, int gridM, int gridN, int Kc,
             unsigned short* __restrict__ outH,
             const float* __restrict__ gq, const float* __restrict__ gk,
             unsigned short* __restrict__ Vtg) {
    __shared__ unsigned short lds[2 * 128 * 64];
    unsigned short* lA = lds;
    unsigned short* lB = lds + 128 * 64;
    int tid = threadIdx.x;
    int wid = tid >> 6, lane = tid & 63;
    int li = lane & 15, lg = lane >> 4;
    int bid = blockIdx.x;
    int mb = bid % gridM;
    int nb = (bid / gridM) % gridN;
    int sp = bid / (gridM * gridN);
    int m0 = mb * 128, n0 = nb * 128;
    int k0 = sp * Kc;
    int wr = (wid >> 1) * 64, wc = (wid & 1) * 64;

    int trow = tid >> 3;                        // 0..31 (staging row within 32-row group)
    int gcol = ((tid & 7) ^ (trow & 7)) * 8;    // pre-swizzled global elem offset
    int sl0 = (lg ^ (li & 7)) * 8;              // ks=0 LDS slot
    int sl1 = ((4 + lg) ^ (li & 7)) * 8;        // ks=1

    f32x4 acc[4][4] = {};

    for (int kk = 0; kk < Kc; kk += 64) {
        #pragma unroll
        for (int l = 0; l < 4; ++l) {
            int row = l * 32 + trow;
            const unsigned short* ga = A  + (size_t)(m0 + row) * K + k0 + kk + gcol;
            const unsigned short* gb = Bw + (size_t)(n0 + row) * K + k0 + kk + gcol;
            unsigned short* la = lA + (l * 256 + wid * 64) * 8;   // wave-uniform base
            unsigned short* lb = lB + (l * 256 + wid * 64) * 8;
            __builtin_amdgcn_global_load_lds((const __attribute__((address_space(1))) void*)ga,
                                             (__attribute__((address_space(3))) void*)la, 16, 0, 0);
            __builtin_amdgcn_global_load_lds((const __attribute__((address_space(1))) void*)gb,
                                             (__attribute__((address_space(3))) void*)lb, 16, 0, 0);
        }
        __syncthreads();
        bf16x8 af[4], bfr[4];
        #pragma unroll
        for (int i = 0; i < 4; ++i)
            af[i] = *(const bf16x8*)(lA + (wr + i * 16 + li) * 64 + sl0);
        #pragma unroll
        for (int j = 0; j < 4; ++j)
            bfr[j] = *(const bf16x8*)(lB + (wc + j * 16 + li) * 64 + sl0);
        #pragma unroll
        for (int i = 0; i < 4; ++i)
            #pragma unroll
            for (int j = 0; j < 4; ++j)
                acc[i][j] = __builtin_amdgcn_mfma_f32_16x16x32_bf16(af[i], bfr[j], acc[i][j], 0, 0, 0);
        #pragma unroll
        for (int i = 0; i < 4; ++i)
            af[i] = *(const bf16x8*)(lA + (wr + i * 16 + li) * 64 + sl1);
        #pragma unroll
        for (int j = 0; j < 4; ++j)
            bfr[j] = *(const bf16x8*)(lB + (wc + j * 16 + li) * 64 + sl1);
        #pragma unroll
        for (int i = 0; i < 4; ++i)
            #pragma unroll
            for (int j = 0; j < 4; ++j)
                acc[i][j] = __builtin_amdgcn_mfma_f32_16x16x32_bf16(af[i], bfr[j], acc[i][j], 0, 0, 0);
        __syncthreads();
    }

    int rb4 = lg * 4;
    size_t poff = (size_t)sp * ((size_t)8192 * N);   // split partial stride (M=8192)
    if (EPI == 5) {
        // wave covers one head's 64 cols (wc + j*16 + li); n0 128-aligned -> typ uniform
        int typ = n0 >> 10;            // 0=Q, 1=K, 2=V
        if (typ == 2) {
            // V: +bias, then transpose via LDS -> Vtg [bh][d][1024]; qkvb16 V never written
            #pragma unroll
            for (int i = 0; i < 4; ++i)
                #pragma unroll
                for (int j = 0; j < 4; ++j)
                    #pragma unroll
                    for (int r = 0; r < 4; ++r)
                        acc[i][j][r] += bias[n0 + wc + j * 16 + li];
            int b = m0 >> 10, t0l = m0 & 1023;
            int h0 = (n0 - 2048) >> 6;
            int half = wid >> 1;                 // wave's t-half (wr = half*64)
            int dl = tid >> 1, seg = tid & 1;    // store mapping
            int bh = b * 16 + h0 + (dl >> 6);
            size_t gb0 = (size_t)bh * 65536 + (size_t)(dl & 63) * 1024 + t0l + seg * 32;
            #pragma unroll
            for (int hh = 0; hh < 2; ++hh) {
                __syncthreads();                 // vt region free
                if (half == hh) {
                    #pragma unroll
                    for (int i = 0; i < 4; ++i)
                        #pragma unroll
                        for (int j = 0; j < 4; ++j) {
                            unsigned short pk[4];
                            #pragma unroll
                            for (int r = 0; r < 4; ++r) pk[r] = f2bf(acc[i][j][r]);
                            // vt[d_local][72] ; t-in-half = i*16 + lg*4
                            *(uint2*)(lds + (wc + j * 16 + li) * 72 + i * 16 + rb4) = *(const uint2*)pk;
                        }
                }
                __syncthreads();
                const unsigned short* src = lds + dl * 72 + seg * 32;
                size_t gdst = gb0 + hh * 64;
                #pragma unroll
                for (int u = 0; u < 4; ++u)
                    *(uint4*)(Vtg + gdst + u * 8) = *(const uint4*)(src + u * 8);
            }
            return;
        }
        float gsc = (typ == 0) ? gq[0] : 8.f * gk[0];
        #pragma unroll
        for (int i = 0; i < 4; ++i) {
            #pragma unroll
            for (int j = 0; j < 4; ++j)
                #pragma unroll
                for (int r = 0; r < 4; ++r)
                    acc[i][j][r] += bias[n0 + wc + j * 16 + li];
            float scl[4];
            #pragma unroll
            for (int r = 0; r < 4; ++r) {
                float s = acc[i][0][r] * acc[i][0][r] + acc[i][1][r] * acc[i][1][r]
                        + acc[i][2][r] * acc[i][2][r] + acc[i][3][r] * acc[i][3][r];
                s += __shfl_xor(s, 1);
                s += __shfl_xor(s, 2);
                s += __shfl_xor(s, 4);
                s += __shfl_xor(s, 8);
                scl[r] = gsc / fmaxf(sqrtf(s), 1e-12f);
            }
            #pragma unroll
            for (int j = 0; j < 4; ++j)
                #pragma unroll
                for (int r = 0; r < 4; ++r) {
                    int row = m0 + wr + i * 16 + rb4 + r;
                    int col = n0 + wc + j * 16 + li;
                    outH[(size_t)row * N + col] = f2bf(acc[i][j][r] * scl[r]);
                }
        }
        return;
    }
    #pragma unroll
    for (int i = 0; i < 4; ++i) {
        #pragma unroll
        for (int j = 0; j < 4; ++j) {
            #pragma unroll
            for (int r = 0; r < 4; ++r) {
                int row = m0 + wr + i * 16 + rb4 + r;
                int col = n0 + wc + j * 16 + li;
                if (EPI == 0) {
                    outH[(size_t)row * N + col] = f2bf(acc[i][j][r] + bias[col]);
                } else if (EPI == 2) {
                    float vv = acc[i][j][r] + bias[col];
                    float a2 = 0.7978845608f * (vv + 0.044715f * vv * vv * vv);
                    float e = __expf(-2.f * fabsf(a2));
                    float th = copysignf((1.f - e) / (1.f + e), a2);
                    outH[(size_t)row * N + col] = f2bf(0.5f * vv * (1.f + th));
                } else {  // EPI == 4: raw bf16 partial
                    outH[poff + (size_t)row * N + col] = f2bf(acc[i][j][r]);
                }
            }
        }
    }
}

// ---------------- proj fixup + residual + fused mlp rmsnorm/modulate ----------------
__global__ void k_fix_norm(const float* __restrict__ x, const unsigned short* __restrict__ P,
                           const float* __restrict__ bias, const float* __restrict__ ada,
                           const float* __restrict__ g2, float* __restrict__ out,
                           unsigned short* __restrict__ h2) {
    int row = blockIdx.x, b = row >> 10, tid = threadIdx.x;
    int c = tid * 4;
    size_t base = (size_t)row * 1024 + c;
    ushort4 p0 = *(const ushort4*)(P + base);
    ushort4 p1 = *(const ushort4*)(P + 8388608 + base);
    float4 xv = *(const float4*)(x + base);
    float4 bi = *(const float4*)(bias + c);
    float4 gt = *(const float4*)(ada + b * 6144 + 2048 + c);
    float4 v;
    v.x = xv.x + gt.x * (bf2f(p0.x) + bf2f(p1.x) + bi.x);
    v.y = xv.y + gt.y * (bf2f(p0.y) + bf2f(p1.y) + bi.y);
    v.z = xv.z + gt.z * (bf2f(p0.z) + bf2f(p1.z) + bi.z);
    v.w = xv.w + gt.w * (bf2f(p0.w) + bf2f(p1.w) + bi.w);
    *(float4*)(out + base) = v;
    float ss = v.x * v.x + v.y * v.y + v.z * v.z + v.w * v.w;
    #pragma unroll
    for (int o = 32; o; o >>= 1) ss += __shfl_xor(ss, o);
    __shared__ float red[4];
    int wid = tid >> 6, lane = tid & 63;
    if (lane == 0) red[wid] = ss;
    __syncthreads();
    float nrm = sqrtf(red[0] + red[1] + red[2] + red[3]);
    float f = g2[0] * 32.f / fmaxf(nrm, 1e-12f);
    float4 sc = *(const float4*)(ada + b * 6144 + 4096 + c);
    float4 sh = *(const float4*)(ada + b * 6144 + 3072 + c);
    ushort4 o;
    o.x = f2bf(v.x * f * (1.f + sc.x) + sh.x);
    o.y = f2bf(v.y * f * (1.f + sc.y) + sh.y);
    o.z = f2bf(v.z * f * (1.f + sc.z) + sh.z);
    o.w = f2bf(v.w * f * (1.f + sc.w) + sh.w);
    *(ushort4*)(h2 + base) = o;
}

// ---------------- fc2 fixup: out = x1 + gate_mlp*(p0+p1+bias) (in place) ----------------
__global__ void k_fixf(const unsigned short* __restrict__ P, const float* __restrict__ bias,
                       const float* __restrict__ ada, float* __restrict__ out) {
    int row = blockIdx.x, b = row >> 10, tid = threadIdx.x;
    int c = tid * 4;
    size_t base = (size_t)row * 1024 + c;
    ushort4 p0 = *(const ushort4*)(P + base);
    ushort4 p1 = *(const ushort4*)(P + 8388608 + base);
    float4 xv = *(const float4*)(out + base);
    float4 bi = *(const float4*)(bias + c);
    float4 gt = *(const float4*)(ada + b * 6144 + 5120 + c);
    float4 v;
    v.x = xv.x + gt.x * (bf2f(p0.x) + bf2f(p1.x) + bi.x);
    v.y = xv.y + gt.y * (bf2f(p0.y) + bf2f(p1.y) + bi.y);
    v.z = xv.z + gt.z * (bf2f(p0.z) + bf2f(p1.z) + bi.z);
    v.w = xv.w + gt.w * (bf2f(p0.w) + bf2f(p1.w) + bi.w);
    *(float4*)(out + base) = v;
}

// ---------------- MFMA attention (QBLK=64, T14-lite: V-only reg prefetch) ----------------
// q/k pre-normalized in the qkv GEMM epilogue; V read from Vtg (written by qkv epilogue).
// K stays on global_load_lds (async, proven). V(kt+1) is prefetched into 4 uint4 regs
// (16 VGPR, transient) and ds_written at the top of tile kt+1. Barriers are RAW s_barrier
// with COUNTED vmcnt(4) at the tile boundary (K batch landed; V prefetch stays in flight
// across the barrier and lands under compute). NOT R16's variant: no K regs, no
// launch_bounds clamp (R16's (256,4)+32 regs spilled to scratch -> 3x slower).
__global__ __launch_bounds__(256)
void k_attn6(const unsigned short* __restrict__ qkv,
             const unsigned short* __restrict__ Vtg,
             unsigned short* __restrict__ outp) {
    __shared__ unsigned short Kt[128 * 64];   // swizzled: granule slot = g ^ (row&7)
    __shared__ unsigned short Vl[64 * 136];   // [d][k], stride 136
    int bh = blockIdx.x;
    int b = bh >> 4, h = bh & 15;
    int t0 = blockIdx.y * 64;
    int tid = threadIdx.x, wid = tid >> 6, lane = tid & 63;
    int li = lane & 15, lg = lane >> 4;
    const size_t bh64k = (size_t)bh * 65536;

    bf16x8 q0, q1;
    {
        int qrow = b * 1024 + t0 + wid * 16 + li;
        const unsigned short* Qg = qkv + (size_t)qrow * 3072 + h * 64 + lg * 8;
        q0 = *(const bf16x8*)Qg;
        q1 = *(const bf16x8*)(Qg + 32);
    }

    // V prefetch coordinates (16B/thread x 4 rows-of-16)
    int vd = tid >> 4, vk = tid & 15;
    const unsigned short* Vg = Vtg + bh64k + (size_t)vd * 1024 + vk * 8;
    uint4 vreg[4];
    #pragma unroll
    for (int i = 0; i < 4; ++i)
        vreg[i] = *(const uint4*)(Vg + (size_t)(i * 16) * 1024);

    f32x4 oacc[4] = {};
    float den = 0.f;

    for (int kt = 0; kt < 8; ++kt) {
        __builtin_amdgcn_s_barrier();   // all waves done reading prev tile's LDS
        // K stage: async global_load_lds (swizzled source, linear dest)
        #pragma unroll
        for (int i = 0; i < 4; ++i) {
            int s = i * 256 + tid;
            int r = s >> 3, c16 = s & 7;
            const unsigned short* src = qkv + (size_t)(b * 1024 + kt * 128 + r) * 3072
                                        + 1024 + h * 64 + ((c16 ^ (r & 7)) * 8);
            unsigned short* dst = Kt + i * 2048 + wid * 512;
            __builtin_amdgcn_global_load_lds((const __attribute__((address_space(1))) void*)src,
                                             (__attribute__((address_space(3))) void*)dst, 16, 0, 0);
        }
        // V stage from regs (compiler waits the prefetch loads, not the K batch)
        #pragma unroll
        for (int i = 0; i < 4; ++i)
            *(uint4*)(Vl + (i * 16 + vd) * 136 + vk * 8) = vreg[i];
        // prefetch V(kt+1); stays in flight across the barrier, lands under compute
        if (kt < 7) {
            #pragma unroll
            for (int i = 0; i < 4; ++i)
                vreg[i] = *(const uint4*)(Vg + (kt + 1) * 128 + (size_t)(i * 16) * 1024);
            asm volatile("s_waitcnt vmcnt(4) lgkmcnt(0)" ::: "memory");  // K landed; V in flight
        } else {
            asm volatile("s_waitcnt vmcnt(0) lgkmcnt(0)" ::: "memory");
        }
        __builtin_amdgcn_s_barrier();

        f32x4 st[8];
        #pragma unroll
        for (int f = 0; f < 8; ++f) {
            int row = f * 16 + li;
            bf16x8 a0 = *(const bf16x8*)(Kt + row * 64 + ((lg       ^ (row & 7)) * 8));
            bf16x8 a1 = *(const bf16x8*)(Kt + row * 64 + (((4 + lg) ^ (row & 7)) * 8));
            f32x4 s = {};
            s = __builtin_amdgcn_mfma_f32_16x16x32_bf16(a0, q0, s, 0, 0, 0);
            s = __builtin_amdgcn_mfma_f32_16x16x32_bf16(a1, q1, s, 0, 0, 0);
            f32x4 e;
            e[0] = __expf(s[0]); e[1] = __expf(s[1]);
            e[2] = __expf(s[2]); e[3] = __expf(s[3]);
            den += e[0] + e[1] + e[2] + e[3];
            st[f] = e;
        }
        #pragma unroll
        for (int ks = 0; ks < 4; ++ks) {
            f32x4 e0 = st[2 * ks], e1 = st[2 * ks + 1];
            bf16x8 pa;
            pa[0] = (__bf16)e0[0]; pa[1] = (__bf16)e0[1]; pa[2] = (__bf16)e0[2]; pa[3] = (__bf16)e0[3];
            pa[4] = (__bf16)e1[0]; pa[5] = (__bf16)e1[1]; pa[6] = (__bf16)e1[2]; pa[7] = (__bf16)e1[3];
            #pragma unroll
            for (int df = 0; df < 4; ++df) {
                const unsigned short* vp = Vl + (df * 16 + li) * 136 + ks * 32 + lg * 4;
                bf16x4 v0 = *(const bf16x4*)vp;
                bf16x4 v1 = *(const bf16x4*)(vp + 16);
                bf16x8 vb = __builtin_shufflevector(v0, v1, 0, 1, 2, 3, 4, 5, 6, 7);
                oacc[df] = __builtin_amdgcn_mfma_f32_16x16x32_bf16(pa, vb, oacc[df], 0, 0, 0);
            }
        }
    }
    den += __shfl_xor(den, 16);
    den += __shfl_xor(den, 32);

    #pragma unroll
    for (int r2 = 0; r2 < 4; ++r2) {
        float dm = __shfl(den, lg * 4 + r2);
        float inv = 1.f / dm;
        int t = t0 + wid * 16 + lg * 4 + r2;
        #pragma unroll
        for (int df = 0; df < 4; ++df) {
            int col = h * 64 + df * 16 + li;
            outp[((size_t)(b * 1024 + t)) * 1024 + col] = f2bf(oacc[df][r2] * inv);
        }
    }
}

extern "C" void kernel_launch(void* const* d_in, const int* in_sizes, int n_in,
                              void* d_out, int out_size, void* d_ws, size_t ws_size,
                              hipStream_t stream) {
    const float* x     = (const float*)d_in[0];
    const float* c     = (const float*)d_in[1];
    const float* g1    = (const float*)d_in[2];
    const float* g2    = (const float*)d_in[3];
    const float* gq    = (const float*)d_in[4];
    const float* gk    = (const float*)d_in[5];
    const float* Wqkv  = (const float*)d_in[6];
    const float* bqkv  = (const float*)d_in[7];
    const float* Wproj = (const float*)d_in[8];
    const float* bproj = (const float*)d_in[9];
    const float* Wfc1  = (const float*)d_in[10];
    const float* bfc1  = (const float*)d_in[11];
    const float* Wfc2  = (const float*)d_in[12];
    const float* bfc2  = (const float*)d_in[13];
    const float* Wada  = (const float*)d_in[14];
    const float* bada  = (const float*)d_in[15];
    float* out = (float*)d_out;

    char* ws = (char*)d_ws;
    unsigned short* wqkv_bf = (unsigned short*)ws; ws += (size_t)3072 * 1024 * 2;
    unsigned short* wproj_bf= (unsigned short*)ws; ws += (size_t)1024 * 1024 * 2;
    unsigned short* wfc1_bf = (unsigned short*)ws; ws += (size_t)4096 * 1024 * 2;
    unsigned short* wfc2_bf = (unsigned short*)ws; ws += (size_t)4096 * 1024 * 2;
    float* ada = (float*)ws;                       ws += (size_t)8 * 6144 * 4;
    unsigned short* hbuf = (unsigned short*)ws;    ws += (size_t)8192 * 1024 * 2;   // h / o / h2
    unsigned short* qkvb16 = (unsigned short*)ws;  ws += (size_t)8192 * 3072 * 2;   // bf16 qkv (q/k pre-normalized)
    unsigned short* Vtg = (unsigned short*)ws;     ws += (size_t)8192 * 64 * 16 * 2;
    unsigned short* Pbuf = (unsigned short*)ws;    ws += (size_t)2 * 8192 * 1024 * 2; // split-K partials
    unsigned short* fc1out = qkvb16;   // 67.1MB = qkvb16(50.3) + Vtg(16.8); both dead at fc1

    // 1) weight converts (one kernel)
    k_cvtall<<<12288, 256, 0, stream>>>(Wqkv, Wproj, Wfc1, Wfc2,
                                        wqkv_bf, wproj_bf, wfc1_bf, wfc2_bf);
    // 2) adaLN
    k_ada<<<dim3(8, 1536), 256, 0, stream>>>(c, Wada, bada, ada);
    // 3) h = modulate(rmsnorm(x), scale_msa, shift_msa)
    k_norm_mod<<<8192, 256, 0, stream>>>(x, ada, g1, hbuf, 0, 1024);
    // 4) qkv = h @ Wqkv^T + bqkv; q/k norm fused; V transposed -> Vtg   grid 64x24
    k_gemm5<5><<<1536, 256, 0, stream>>>(hbuf, wqkv_bf, bqkv, 3072, 1024, 64, 24, 1024,
                                         qkvb16, gq, gk, Vtg);
    // 5) attention (QBLK=64, V reg-prefetch + counted vmcnt) -> o (bf16, reuse hbuf)
    k_attn6<<<dim3(128, 16), 256, 0, stream>>>(qkvb16, Vtg, hbuf);
    // 6) proj partials (split-K=2): grid 64x8x2 = 1024 blocks
    k_gemm5<4><<<1024, 256, 0, stream>>>(hbuf, wproj_bf, bproj, 1024, 1024, 64, 8, 512,
                                         Pbuf, nullptr, nullptr, nullptr);
    // 7) x1 = x + gate_msa*(p0+p1+bias) -> out; h2 = modulate(rmsnorm(x1)) -> hbuf
    k_fix_norm<<<8192, 256, 0, stream>>>(x, Pbuf, bproj, ada, g2, out, hbuf);
    // 8) fc1 + gelu -> bf16   grid 64x32
    k_gemm5<2><<<2048, 256, 0, stream>>>(hbuf, wfc1_bf, bfc1, 4096, 1024, 64, 32, 1024,
                                         fc1out, nullptr, nullptr, nullptr);
    // 9) fc2 partials (split-K=2): grid 64x8x2 = 1024 blocks
    k_gemm5<4><<<1024, 256, 0, stream>>>(fc1out, wfc2_bf, bfc2, 1024, 4096, 64, 8, 2048,
                                         Pbuf, nullptr, nullptr, nullptr);
    // 10) out = x1 + gate_mlp*(p0+p1+bias)
    k_fixf<<<8192, 256, 0, stream>>>(Pbuf, bfc2, ada, out);
}

// Round 19
// 386.675 us; speedup vs baseline: 1.0857x; 1.0857x over previous
//
#include <hip/hip_runtime.h>
#include <hip/hip_bf16.h>
#include <math.h>

typedef __bf16 bf16x8 __attribute__((ext_vector_type(8)));
typedef __bf16 bf16x4 __attribute__((ext_vector_type(4)));
typedef float  f32x4  __attribute__((ext_vector_type(4)));

#define DEV static __device__ __forceinline__

DEV unsigned short f2bf(float f) {
    unsigned u = __builtin_bit_cast(unsigned, f);
    u += 0x7fffu + ((u >> 16) & 1u);     // RNE
    return (unsigned short)(u >> 16);
}
DEV float bf2f(unsigned short u) {
    unsigned x = ((unsigned)u) << 16;
    return __builtin_bit_cast(float, x);
}

// ---------------- fused fp32 -> bf16 weight convert (all 4 weights) ----------------
__global__ void k_cvtall(const float* __restrict__ a, const float* __restrict__ b,
                         const float* __restrict__ c, const float* __restrict__ d,
                         unsigned short* __restrict__ oa, unsigned short* __restrict__ ob,
                         unsigned short* __restrict__ oc, unsigned short* __restrict__ od) {
    size_t i = (size_t)blockIdx.x * 1024 + threadIdx.x * 4;
    const float* src; unsigned short* dst; size_t off;
    if (i < 3145728)      { src = a; dst = oa; off = i; }
    else if (i < 4194304) { src = b; dst = ob; off = i - 3145728; }
    else if (i < 8388608) { src = c; dst = oc; off = i - 4194304; }
    else                  { src = d; dst = od; off = i - 8388608; }
    float4 v = *(const float4*)(src + off);
    ushort4 o;
    o.x = f2bf(v.x); o.y = f2bf(v.y); o.z = f2bf(v.z); o.w = f2bf(v.w);
    *(ushort4*)(dst + off) = o;
}

// ---------------- adaLN: ada = silu(c) @ Wada^T + bada ----------------
__global__ void k_ada(const float* __restrict__ c, const float* __restrict__ Wada,
                      const float* __restrict__ bada, float* __restrict__ ada) {
    __shared__ float sc[1024];
    int b = blockIdx.x;
    int tid = threadIdx.x;
    for (int k = tid; k < 1024; k += 256) {
        float x = c[b * 1024 + k];
        sc[k] = x / (1.f + __expf(-x));
    }
    __syncthreads();
    int wid = tid >> 6, lane = tid & 63;
    int n = blockIdx.y * 4 + wid;
    const float* wr = Wada + (size_t)n * 1024;
    float acc = 0.f;
    #pragma unroll
    for (int k = 0; k < 1024; k += 64) acc += sc[k + lane] * wr[k + lane];
    #pragma unroll
    for (int o = 32; o; o >>= 1) acc += __shfl_xor(acc, o);
    if (lane == 0) ada[b * 6144 + n] = acc + bada[n];
}

// ---------------- fused rmsnorm + modulate -> bf16 (msa branch) ----------------
__global__ void k_norm_mod(const float* __restrict__ x, const float* __restrict__ ada,
                           const float* __restrict__ g, unsigned short* __restrict__ h,
                           int shift_off, int scale_off) {
    int row = blockIdx.x;
    int b = row >> 10;
    int tid = threadIdx.x;
    float4 v = *(const float4*)(x + (size_t)row * 1024 + tid * 4);
    float ss = v.x * v.x + v.y * v.y + v.z * v.z + v.w * v.w;
    #pragma unroll
    for (int o = 32; o; o >>= 1) ss += __shfl_xor(ss, o);
    __shared__ float red[4];
    int wid = tid >> 6, lane = tid & 63;
    if (lane == 0) red[wid] = ss;
    __syncthreads();
    float nrm = sqrtf(red[0] + red[1] + red[2] + red[3]);
    float f = g[0] * 32.f / fmaxf(nrm, 1e-12f);
    float4 s4 = *(const float4*)(ada + b * 6144 + scale_off + tid * 4);
    float4 h4 = *(const float4*)(ada + b * 6144 + shift_off + tid * 4);
    ushort4 o;
    o.x = f2bf(v.x * f * (1.f + s4.x) + h4.x);
    o.y = f2bf(v.y * f * (1.f + s4.y) + h4.y);
    o.z = f2bf(v.z * f * (1.f + s4.z) + h4.z);
    o.w = f2bf(v.w * f * (1.f + s4.w) + h4.w);
    *(ushort4*)(h + (size_t)row * 1024 + tid * 4) = o;
}

// ============ m97-structure bf16 GEMM, BK=64, optional split-K ============
// 128x128 tile, BK=64, 256 threads (4 waves), 32KB LDS single-buffered.
// __launch_bounds__(256,4): 60 VGPR, NO spills (R8 proved (256,5) spills acc -> 2.3x slower).
// Rows = 128B = 8 granules; LDS slot = granule ^ (row&7) (measured ZERO bank conflicts),
// applied involutively on the global source. DO NOT replace with deep pipelines:
// R5 (3-buf ring) and R11 (8-phase port) both measured SLOWER (113/102 vs 84 us).
// EPI: 0 = +bias -> bf16 | 2 = gelu(+bias) -> bf16 | 4 = raw partial -> bf16 at sp*M*N
//      5 = qkv: Q/K fused per-head rms-norm -> outH; V transposed through LDS -> Vtg
template <int EPI>
__global__ __launch_bounds__(256, 4)
void k_gemm5(const unsigned short* __restrict__ A, const unsigned short* __restrict__ Bw,
             const float* __restrict__ bias, int N, int K, int gridM, int gridN, int Kc,
             unsigned short* __restrict__ outH,
             const float* __restrict__ gq, const float* __restrict__ gk,
             unsigned short* __restrict__ Vtg) {
    __shared__ unsigned short lds[2 * 128 * 64];
    unsigned short* lA = lds;
    unsigned short* lB = lds + 128 * 64;
    int tid = threadIdx.x;
    int wid = tid >> 6, lane = tid & 63;
    int li = lane & 15, lg = lane >> 4;
    int bid = blockIdx.x;
    int mb = bid % gridM;
    int nb = (bid / gridM) % gridN;
    int sp = bid / (gridM * gridN);
    int m0 = mb * 128, n0 = nb * 128;
    int k0 = sp * Kc;
    int wr = (wid >> 1) * 64, wc = (wid & 1) * 64;

    int trow = tid >> 3;                        // 0..31 (staging row within 32-row group)
    int gcol = ((tid & 7) ^ (trow & 7)) * 8;    // pre-swizzled global elem offset
    int sl0 = (lg ^ (li & 7)) * 8;              // ks=0 LDS slot
    int sl1 = ((4 + lg) ^ (li & 7)) * 8;        // ks=1

    f32x4 acc[4][4] = {};

    for (int kk = 0; kk < Kc; kk += 64) {
        #pragma unroll
        for (int l = 0; l < 4; ++l) {
            int row = l * 32 + trow;
            const unsigned short* ga = A  + (size_t)(m0 + row) * K + k0 + kk + gcol;
            const unsigned short* gb = Bw + (size_t)(n0 + row) * K + k0 + kk + gcol;
            unsigned short* la = lA + (l * 256 + wid * 64) * 8;   // wave-uniform base
            unsigned short* lb = lB + (l * 256 + wid * 64) * 8;
            __builtin_amdgcn_global_load_lds((const __attribute__((address_space(1))) void*)ga,
                                             (__attribute__((address_space(3))) void*)la, 16, 0, 0);
            __builtin_amdgcn_global_load_lds((const __attribute__((address_space(1))) void*)gb,
                                             (__attribute__((address_space(3))) void*)lb, 16, 0, 0);
        }
        __syncthreads();
        bf16x8 af[4], bfr[4];
        #pragma unroll
        for (int i = 0; i < 4; ++i)
            af[i] = *(const bf16x8*)(lA + (wr + i * 16 + li) * 64 + sl0);
        #pragma unroll
        for (int j = 0; j < 4; ++j)
            bfr[j] = *(const bf16x8*)(lB + (wc + j * 16 + li) * 64 + sl0);
        #pragma unroll
        for (int i = 0; i < 4; ++i)
            #pragma unroll
            for (int j = 0; j < 4; ++j)
                acc[i][j] = __builtin_amdgcn_mfma_f32_16x16x32_bf16(af[i], bfr[j], acc[i][j], 0, 0, 0);
        #pragma unroll
        for (int i = 0; i < 4; ++i)
            af[i] = *(const bf16x8*)(lA + (wr + i * 16 + li) * 64 + sl1);
        #pragma unroll
        for (int j = 0; j < 4; ++j)
            bfr[j] = *(const bf16x8*)(lB + (wc + j * 16 + li) * 64 + sl1);
        #pragma unroll
        for (int i = 0; i < 4; ++i)
            #pragma unroll
            for (int j = 0; j < 4; ++j)
                acc[i][j] = __builtin_amdgcn_mfma_f32_16x16x32_bf16(af[i], bfr[j], acc[i][j], 0, 0, 0);
        __syncthreads();
    }

    int rb4 = lg * 4;
    size_t poff = (size_t)sp * ((size_t)8192 * N);   // split partial stride (M=8192)
    if (EPI == 5) {
        // wave covers one head's 64 cols (wc + j*16 + li); n0 128-aligned -> typ uniform
        int typ = n0 >> 10;            // 0=Q, 1=K, 2=V
        if (typ == 2) {
            // V: +bias, then transpose via LDS -> Vtg [bh][d][1024]; qkvb16 V never written
            #pragma unroll
            for (int i = 0; i < 4; ++i)
                #pragma unroll
                for (int j = 0; j < 4; ++j)
                    #pragma unroll
                    for (int r = 0; r < 4; ++r)
                        acc[i][j][r] += bias[n0 + wc + j * 16 + li];
            int b = m0 >> 10, t0l = m0 & 1023;
            int h0 = (n0 - 2048) >> 6;
            int half = wid >> 1;                 // wave's t-half (wr = half*64)
            int dl = tid >> 1, seg = tid & 1;    // store mapping
            int bh = b * 16 + h0 + (dl >> 6);
            size_t gb0 = (size_t)bh * 65536 + (size_t)(dl & 63) * 1024 + t0l + seg * 32;
            #pragma unroll
            for (int hh = 0; hh < 2; ++hh) {
                __syncthreads();                 // vt region free
                if (half == hh) {
                    #pragma unroll
                    for (int i = 0; i < 4; ++i)
                        #pragma unroll
                        for (int j = 0; j < 4; ++j) {
                            unsigned short pk[4];
                            #pragma unroll
                            for (int r = 0; r < 4; ++r) pk[r] = f2bf(acc[i][j][r]);
                            // vt[d_local][72] ; t-in-half = i*16 + lg*4
                            *(uint2*)(lds + (wc + j * 16 + li) * 72 + i * 16 + rb4) = *(const uint2*)pk;
                        }
                }
                __syncthreads();
                const unsigned short* src = lds + dl * 72 + seg * 32;
                size_t gdst = gb0 + hh * 64;
                #pragma unroll
                for (int u = 0; u < 4; ++u)
                    *(uint4*)(Vtg + gdst + u * 8) = *(const uint4*)(src + u * 8);
            }
            return;
        }
        float gsc = (typ == 0) ? gq[0] : 8.f * gk[0];
        #pragma unroll
        for (int i = 0; i < 4; ++i) {
            #pragma unroll
            for (int j = 0; j < 4; ++j)
                #pragma unroll
                for (int r = 0; r < 4; ++r)
                    acc[i][j][r] += bias[n0 + wc + j * 16 + li];
            float scl[4];
            #pragma unroll
            for (int r = 0; r < 4; ++r) {
                float s = acc[i][0][r] * acc[i][0][r] + acc[i][1][r] * acc[i][1][r]
                        + acc[i][2][r] * acc[i][2][r] + acc[i][3][r] * acc[i][3][r];
                s += __shfl_xor(s, 1);
                s += __shfl_xor(s, 2);
                s += __shfl_xor(s, 4);
                s += __shfl_xor(s, 8);
                scl[r] = gsc / fmaxf(sqrtf(s), 1e-12f);
            }
            #pragma unroll
            for (int j = 0; j < 4; ++j)
                #pragma unroll
                for (int r = 0; r < 4; ++r) {
                    int row = m0 + wr + i * 16 + rb4 + r;
                    int col = n0 + wc + j * 16 + li;
                    outH[(size_t)row * N + col] = f2bf(acc[i][j][r] * scl[r]);
                }
        }
        return;
    }
    #pragma unroll
    for (int i = 0; i < 4; ++i) {
        #pragma unroll
        for (int j = 0; j < 4; ++j) {
            #pragma unroll
            for (int r = 0; r < 4; ++r) {
                int row = m0 + wr + i * 16 + rb4 + r;
                int col = n0 + wc + j * 16 + li;
                if (EPI == 0) {
                    outH[(size_t)row * N + col] = f2bf(acc[i][j][r] + bias[col]);
                } else if (EPI == 2) {
                    float vv = acc[i][j][r] + bias[col];
                    float a2 = 0.7978845608f * (vv + 0.044715f * vv * vv * vv);
                    float e = __expf(-2.f * fabsf(a2));
                    float th = copysignf((1.f - e) / (1.f + e), a2);
                    outH[(size_t)row * N + col] = f2bf(0.5f * vv * (1.f + th));
                } else {  // EPI == 4: raw bf16 partial
                    outH[poff + (size_t)row * N + col] = f2bf(acc[i][j][r]);
                }
            }
        }
    }
}

// ---------------- proj fixup + residual + fused mlp rmsnorm/modulate ----------------
__global__ void k_fix_norm(const float* __restrict__ x, const unsigned short* __restrict__ P,
                           const float* __restrict__ bias, const float* __restrict__ ada,
                           const float* __restrict__ g2, float* __restrict__ out,
                           unsigned short* __restrict__ h2) {
    int row = blockIdx.x, b = row >> 10, tid = threadIdx.x;
    int c = tid * 4;
    size_t base = (size_t)row * 1024 + c;
    ushort4 p0 = *(const ushort4*)(P + base);
    ushort4 p1 = *(const ushort4*)(P + 8388608 + base);
    float4 xv = *(const float4*)(x + base);
    float4 bi = *(const float4*)(bias + c);
    float4 gt = *(const float4*)(ada + b * 6144 + 2048 + c);
    float4 v;
    v.x = xv.x + gt.x * (bf2f(p0.x) + bf2f(p1.x) + bi.x);
    v.y = xv.y + gt.y * (bf2f(p0.y) + bf2f(p1.y) + bi.y);
    v.z = xv.z + gt.z * (bf2f(p0.z) + bf2f(p1.z) + bi.z);
    v.w = xv.w + gt.w * (bf2f(p0.w) + bf2f(p1.w) + bi.w);
    *(float4*)(out + base) = v;
    float ss = v.x * v.x + v.y * v.y + v.z * v.z + v.w * v.w;
    #pragma unroll
    for (int o = 32; o; o >>= 1) ss += __shfl_xor(ss, o);
    __shared__ float red[4];
    int wid = tid >> 6, lane = tid & 63;
    if (lane == 0) red[wid] = ss;
    __syncthreads();
    float nrm = sqrtf(red[0] + red[1] + red[2] + red[3]);
    float f = g2[0] * 32.f / fmaxf(nrm, 1e-12f);
    float4 sc = *(const float4*)(ada + b * 6144 + 4096 + c);
    float4 sh = *(const float4*)(ada + b * 6144 + 3072 + c);
    ushort4 o;
    o.x = f2bf(v.x * f * (1.f + sc.x) + sh.x);
    o.y = f2bf(v.y * f * (1.f + sc.y) + sh.y);
    o.z = f2bf(v.z * f * (1.f + sc.z) + sh.z);
    o.w = f2bf(v.w * f * (1.f + sc.w) + sh.w);
    *(ushort4*)(h2 + base) = o;
}

// ---------------- fc2 fixup: out = x1 + gate_mlp*(p0+p1+bias) (in place) ----------------
__global__ void k_fixf(const unsigned short* __restrict__ P, const float* __restrict__ bias,
                       const float* __restrict__ ada, float* __restrict__ out) {
    int row = blockIdx.x, b = row >> 10, tid = threadIdx.x;
    int c = tid * 4;
    size_t base = (size_t)row * 1024 + c;
    ushort4 p0 = *(const ushort4*)(P + base);
    ushort4 p1 = *(const ushort4*)(P + 8388608 + base);
    float4 xv = *(const float4*)(out + base);
    float4 bi = *(const float4*)(bias + c);
    float4 gt = *(const float4*)(ada + b * 6144 + 5120 + c);
    float4 v;
    v.x = xv.x + gt.x * (bf2f(p0.x) + bf2f(p1.x) + bi.x);
    v.y = xv.y + gt.y * (bf2f(p0.y) + bf2f(p1.y) + bi.y);
    v.z = xv.z + gt.z * (bf2f(p0.z) + bf2f(p1.z) + bi.z);
    v.w = xv.w + gt.w * (bf2f(p0.w) + bf2f(p1.w) + bi.w);
    *(float4*)(out + base) = v;
}

// ---------------- MFMA attention (QBLK=64, R15-exact structure) ----------------
// q/k pre-normalized in the qkv GEMM epilogue; V read from Vtg (written by qkv epilogue).
// K staged via global_load_lds (swizzled source), V reg-staged to padded LDS in-phase.
// DO NOT add register prefetch in any form: R16 (K+V regs) and R18 (V-only regs) both
// spilled to scratch and regressed 1.5-3x. This simple structure is the measured optimum.
__global__ __launch_bounds__(256)
void k_attn3(const unsigned short* __restrict__ qkv,
             const unsigned short* __restrict__ Vtg,
             unsigned short* __restrict__ outp) {
    __shared__ unsigned short Kt[128 * 64];   // swizzled: granule slot = g ^ (row&7)
    __shared__ unsigned short Vl[64 * 136];   // [d][k], stride 136
    int bh = blockIdx.x;
    int b = bh >> 4, h = bh & 15;
    int t0 = blockIdx.y * 64;
    int tid = threadIdx.x, wid = tid >> 6, lane = tid & 63;
    int li = lane & 15, lg = lane >> 4;
    const size_t bh64k = (size_t)bh * 65536;

    bf16x8 q0, q1;
    {
        int qrow = b * 1024 + t0 + wid * 16 + li;
        const unsigned short* Qg = qkv + (size_t)qrow * 3072 + h * 64 + lg * 8;
        q0 = *(const bf16x8*)Qg;
        q1 = *(const bf16x8*)(Qg + 32);
    }
    f32x4 oacc[4] = {};
    float den = 0.f;

    for (int kt = 0; kt < 8; ++kt) {
        __syncthreads();   // prev tile compute done before Kt/Vl overwrite
        #pragma unroll
        for (int i = 0; i < 4; ++i) {
            int s = i * 256 + tid;
            int r = s >> 3, c16 = s & 7;
            const unsigned short* src = qkv + (size_t)(b * 1024 + kt * 128 + r) * 3072
                                        + 1024 + h * 64 + ((c16 ^ (r & 7)) * 8);
            unsigned short* dst = Kt + i * 2048 + wid * 512;
            __builtin_amdgcn_global_load_lds((const __attribute__((address_space(1))) void*)src,
                                             (__attribute__((address_space(3))) void*)dst, 16, 0, 0);
        }
        #pragma unroll
        for (int i = 0; i < 4; ++i) {
            int s = i * 256 + tid;
            int d = s >> 4, k16 = s & 15;
            uint4 v = *(const uint4*)(Vtg + bh64k + (size_t)d * 1024 + kt * 128 + k16 * 8);
            *(uint4*)(Vl + d * 136 + k16 * 8) = v;
        }
        __syncthreads();

        f32x4 st[8];
        #pragma unroll
        for (int f = 0; f < 8; ++f) {
            int row = f * 16 + li;
            bf16x8 a0 = *(const bf16x8*)(Kt + row * 64 + ((lg       ^ (row & 7)) * 8));
            bf16x8 a1 = *(const bf16x8*)(Kt + row * 64 + (((4 + lg) ^ (row & 7)) * 8));
            f32x4 s = {};
            s = __builtin_amdgcn_mfma_f32_16x16x32_bf16(a0, q0, s, 0, 0, 0);
            s = __builtin_amdgcn_mfma_f32_16x16x32_bf16(a1, q1, s, 0, 0, 0);
            f32x4 e;
            e[0] = __expf(s[0]); e[1] = __expf(s[1]);
            e[2] = __expf(s[2]); e[3] = __expf(s[3]);
            den += e[0] + e[1] + e[2] + e[3];
            st[f] = e;
        }
        #pragma unroll
        for (int ks = 0; ks < 4; ++ks) {
            f32x4 e0 = st[2 * ks], e1 = st[2 * ks + 1];
            bf16x8 pa;
            pa[0] = (__bf16)e0[0]; pa[1] = (__bf16)e0[1]; pa[2] = (__bf16)e0[2]; pa[3] = (__bf16)e0[3];
            pa[4] = (__bf16)e1[0]; pa[5] = (__bf16)e1[1]; pa[6] = (__bf16)e1[2]; pa[7] = (__bf16)e1[3];
            #pragma unroll
            for (int df = 0; df < 4; ++df) {
                const unsigned short* vp = Vl + (df * 16 + li) * 136 + ks * 32 + lg * 4;
                bf16x4 v0 = *(const bf16x4*)vp;
                bf16x4 v1 = *(const bf16x4*)(vp + 16);
                bf16x8 vb = __builtin_shufflevector(v0, v1, 0, 1, 2, 3, 4, 5, 6, 7);
                oacc[df] = __builtin_amdgcn_mfma_f32_16x16x32_bf16(pa, vb, oacc[df], 0, 0, 0);
            }
        }
    }
    den += __shfl_xor(den, 16);
    den += __shfl_xor(den, 32);

    #pragma unroll
    for (int r2 = 0; r2 < 4; ++r2) {
        float dm = __shfl(den, lg * 4 + r2);
        float inv = 1.f / dm;
        int t = t0 + wid * 16 + lg * 4 + r2;
        #pragma unroll
        for (int df = 0; df < 4; ++df) {
            int col = h * 64 + df * 16 + li;
            outp[((size_t)(b * 1024 + t)) * 1024 + col] = f2bf(oacc[df][r2] * inv);
        }
    }
}

extern "C" void kernel_launch(void* const* d_in, const int* in_sizes, int n_in,
                              void* d_out, int out_size, void* d_ws, size_t ws_size,
                              hipStream_t stream) {
    const float* x     = (const float*)d_in[0];
    const float* c     = (const float*)d_in[1];
    const float* g1    = (const float*)d_in[2];
    const float* g2    = (const float*)d_in[3];
    const float* gq    = (const float*)d_in[4];
    const float* gk    = (const float*)d_in[5];
    const float* Wqkv  = (const float*)d_in[6];
    const float* bqkv  = (const float*)d_in[7];
    const float* Wproj = (const float*)d_in[8];
    const float* bproj = (const float*)d_in[9];
    const float* Wfc1  = (const float*)d_in[10];
    const float* bfc1  = (const float*)d_in[11];
    const float* Wfc2  = (const float*)d_in[12];
    const float* bfc2  = (const float*)d_in[13];
    const float* Wada  = (const float*)d_in[14];
    const float* bada  = (const float*)d_in[15];
    float* out = (float*)d_out;

    char* ws = (char*)d_ws;
    unsigned short* wqkv_bf = (unsigned short*)ws; ws += (size_t)3072 * 1024 * 2;
    unsigned short* wproj_bf= (unsigned short*)ws; ws += (size_t)1024 * 1024 * 2;
    unsigned short* wfc1_bf = (unsigned short*)ws; ws += (size_t)4096 * 1024 * 2;
    unsigned short* wfc2_bf = (unsigned short*)ws; ws += (size_t)4096 * 1024 * 2;
    float* ada = (float*)ws;                       ws += (size_t)8 * 6144 * 4;
    unsigned short* hbuf = (unsigned short*)ws;    ws += (size_t)8192 * 1024 * 2;   // h / o / h2
    unsigned short* qkvb16 = (unsigned short*)ws;  ws += (size_t)8192 * 3072 * 2;   // bf16 qkv (q/k pre-normalized)
    unsigned short* Vtg = (unsigned short*)ws;     ws += (size_t)8192 * 64 * 16 * 2;
    unsigned short* Pbuf = (unsigned short*)ws;    ws += (size_t)2 * 8192 * 1024 * 2; // split-K partials
    unsigned short* fc1out = qkvb16;   // 67.1MB = qkvb16(50.3) + Vtg(16.8); both dead at fc1

    // 1) weight converts (one kernel)
    k_cvtall<<<12288, 256, 0, stream>>>(Wqkv, Wproj, Wfc1, Wfc2,
                                        wqkv_bf, wproj_bf, wfc1_bf, wfc2_bf);
    // 2) adaLN
    k_ada<<<dim3(8, 1536), 256, 0, stream>>>(c, Wada, bada, ada);
    // 3) h = modulate(rmsnorm(x), scale_msa, shift_msa)
    k_norm_mod<<<8192, 256, 0, stream>>>(x, ada, g1, hbuf, 0, 1024);
    // 4) qkv = h @ Wqkv^T + bqkv; q/k norm fused; V transposed -> Vtg   grid 64x24
    k_gemm5<5><<<1536, 256, 0, stream>>>(hbuf, wqkv_bf, bqkv, 3072, 1024, 64, 24, 1024,
                                         qkvb16, gq, gk, Vtg);
    // 5) attention (QBLK=64) -> o (bf16, reuse hbuf)
    k_attn3<<<dim3(128, 16), 256, 0, stream>>>(qkvb16, Vtg, hbuf);
    // 6) proj partials (split-K=2): grid 64x8x2 = 1024 blocks
    k_gemm5<4><<<1024, 256, 0, stream>>>(hbuf, wproj_bf, bproj, 1024, 1024, 64, 8, 512,
                                         Pbuf, nullptr, nullptr, nullptr);
    // 7) x1 = x + gate_msa*(p0+p1+bias) -> out; h2 = modulate(rmsnorm(x1)) -> hbuf
    k_fix_norm<<<8192, 256, 0, stream>>>(x, Pbuf, bproj, ada, g2, out, hbuf);
    // 8) fc1 + gelu -> bf16   grid 64x32
    k_gemm5<2><<<2048, 256, 0, stream>>>(hbuf, wfc1_bf, bfc1, 4096, 1024, 64, 32, 1024,
                                         fc1out, nullptr, nullptr, nullptr);
    // 9) fc2 partials (split-K=2): grid 64x8x2 = 1024 blocks
    k_gemm5<4><<<1024, 256, 0, stream>>>(fc1out, wfc2_bf, bfc2, 1024, 4096, 64, 8, 2048,
                                         Pbuf, nullptr, nullptr, nullptr);
    // 10) out = x1 + gate_mlp*(p0+p1+bias)
    k_fixf<<<8192, 256, 0, stream>>>(Pbuf, bfc2, ada, out);
}